// Round 2
// baseline (187.913 us; speedup 1.0000x reference)
//
#include <hip/hip_runtime.h>

#define N 8192
#define KD 128
#define NCLS 10
#define NCH 16
#define CHUNK (N / NCH) /* 512 */

typedef __attribute__((ext_vector_type(8))) short short8;
typedef __attribute__((ext_vector_type(4))) float floatx4;

__device__ __forceinline__ unsigned short f2bf(float x) {
    unsigned u = __float_as_uint(x);
    u += 0x7fffu + ((u >> 16) & 1u);   // round-to-nearest-even
    return (unsigned short)(u >> 16);
}

// ---------------- k_zero: zero cnt/ticket/acc/S ----------------
__global__ void k_zero(int* __restrict__ cnt, float* __restrict__ acc,
                       float* __restrict__ S) {
    int t = threadIdx.x;
    if (t < 16) cnt[t] = 0;
    if (t == 0) acc[0] = 0.f;
    for (int i = t; i < NCLS * KD; i += 256) S[i] = 0.f;
}

// ---------------- k_prep: class counts + class feature sums ----------------
// 128 blocks x 256 threads; block handles 64 rows; t = h*128 + k
__global__ void k_prep(const float* __restrict__ F, const int* __restrict__ tgt,
                       float* __restrict__ S, int* __restrict__ cnt) {
    int t = threadIdx.x;
    int k = t & 127;
    int h = t >> 7;
    int row0 = blockIdx.x * 64;

    __shared__ int hist[NCLS];
    if (t < NCLS) hist[t] = 0;
    __syncthreads();
    if (t < 64) atomicAdd(&hist[tgt[row0 + t]], 1);

    float local[NCLS];
#pragma unroll
    for (int c = 0; c < NCLS; ++c) local[c] = 0.f;
    for (int ii = 0; ii < 32; ++ii) {
        int i = row0 + h * 32 + ii;
        float v = F[i * KD + k];
        int c = tgt[i];
#pragma unroll
        for (int cc = 0; cc < NCLS; ++cc) local[cc] += (cc == c) ? v : 0.f;
    }
    __shared__ float red[2][NCLS][KD];   // 10 KiB
#pragma unroll
    for (int cc = 0; cc < NCLS; ++cc) red[h][cc][k] = local[cc];
    __syncthreads();
    if (h == 0) {
#pragma unroll
        for (int cc = 0; cc < NCLS; ++cc)
            atomicAdd(&S[cc * KD + k], red[0][cc][k] + red[1][cc][k]);
        if (t < NCLS) atomicAdd(&cnt[t], hist[t]);
    }
}

// ---------------- k_row: posdot + diag shift + bf16 conversion ----------------
__global__ void k_row(const float* __restrict__ F, const int* __restrict__ tgt,
                      const float* __restrict__ S, float* __restrict__ posdot,
                      float* __restrict__ diag10,
                      unsigned short* __restrict__ A10, unsigned short* __restrict__ B1) {
    int row = blockIdx.x * 4 + (threadIdx.x >> 6);
    int lane = threadIdx.x & 63;
    float2 fv = *(const float2*)(F + row * KD + lane * 2);
    int c = tgt[row];
    float2 sv = *(const float2*)(S + c * KD + lane * 2);
    float dS = fv.x * sv.x + fv.y * sv.y;
    float sq = fv.x * fv.x + fv.y * fv.y;
#pragma unroll
    for (int off = 32; off >= 1; off >>= 1) {
        dS += __shfl_xor(dS, off);
        sq += __shfl_xor(sq, off);
    }
    if (lane == 0) {
        posdot[row] = dS - sq;       // sum over positives of raw dot
        diag10[row] = 10.f * sq;     // the softmax shift (== diag logit)
    }
    ushort2 av, bv;
    av.x = f2bf(10.f * fv.x); av.y = f2bf(10.f * fv.y);
    bv.x = f2bf(fv.x);        bv.y = f2bf(fv.y);
    *(ushort2*)(A10 + row * KD + lane * 2) = av;
    *(ushort2*)(B1 + row * KD + lane * 2) = bv;
}

// ---------------- k_pair: streaming pairwise sum-exp (fixed shift) ----------------
// Grid: (N/128 row blocks, NCH chunks). Block 256 = 4 waves of 32 rows each.
// Wave tile: 32 rows x 128 cols per j-step (2x8 MFMA 16x16x32 tiles, K=128).
__global__ __launch_bounds__(256, 3) void k_pair(const unsigned short* __restrict__ A10,
                                                 const unsigned short* __restrict__ B1,
                                                 const float* __restrict__ diag10,
                                                 float* __restrict__ ps) {
    int bx = blockIdx.x, ch = blockIdx.y;
    int tid = threadIdx.x;
    int wid = tid >> 6, lane = tid & 63;
    int quad = lane >> 4, l16 = lane & 15;
    int wg_row0 = bx * 128;
    int row0 = wg_row0 + wid * 32;

    // A fragments resident for the whole sweep: A[m=l16][k=quad*8+j]
    short8 af[2][4];
#pragma unroll
    for (int ti = 0; ti < 2; ++ti)
#pragma unroll
        for (int ks = 0; ks < 4; ++ks) {
            int r = row0 + ti * 16 + l16;
            af[ti][ks] = *(const short8*)(A10 + r * KD + ks * 32 + quad * 8);
        }

    // per-slot shift (row of this lane's acc element): row = row0+ti*16+quad*4+r
    float Mr[8];
#pragma unroll
    for (int ti = 0; ti < 2; ++ti)
#pragma unroll
        for (int r = 0; r < 4; ++r)
            Mr[ti * 4 + r] = diag10[row0 + ti * 16 + quad * 4 + r];

    float s[8];
#pragma unroll
    for (int i = 0; i < 8; ++i) s[i] = 0.f;

    int ccol0 = ch * CHUNK;
    for (int jj = 0; jj < CHUNK / 128; ++jj) {
        int col0 = ccol0 + jj * 128;
        floatx4 acc[2][8];
#pragma unroll
        for (int ti = 0; ti < 2; ++ti)
#pragma unroll
            for (int tj = 0; tj < 8; ++tj)
                acc[ti][tj] = (floatx4){0.f, 0.f, 0.f, 0.f};

#pragma unroll
        for (int ks = 0; ks < 4; ++ks) {
            short8 bf[8];                // B[k=quad*8+j][n=l16] = row (col) of B1
#pragma unroll
            for (int tj = 0; tj < 8; ++tj) {
                int cidx = col0 + tj * 16 + l16;
                bf[tj] = *(const short8*)(B1 + cidx * KD + ks * 32 + quad * 8);
            }
#pragma unroll
            for (int ti = 0; ti < 2; ++ti)
#pragma unroll
                for (int tj = 0; tj < 8; ++tj)
                    acc[ti][tj] = __builtin_amdgcn_mfma_f32_16x16x32_bf16(
                        af[ti][ks], bf[tj], acc[ti][tj], 0, 0, 0);
        }

        // skip check: does ANY element of this 32x128 tile survive exp(v - M)?
        float dmax = -INFINITY;
#pragma unroll
        for (int ti = 0; ti < 2; ++ti)
#pragma unroll
            for (int r = 0; r < 4; ++r) {
                int slot = ti * 4 + r;
                float mb = fmaxf(
                    fmaxf(fmaxf(acc[ti][0][r], acc[ti][1][r]),
                          fmaxf(acc[ti][2][r], acc[ti][3][r])),
                    fmaxf(fmaxf(acc[ti][4][r], acc[ti][5][r]),
                          fmaxf(acc[ti][6][r], acc[ti][7][r])));
                dmax = fmaxf(dmax, mb - Mr[slot]);
            }
        // exp(x) for x < -60: contribution < 8192*exp(-60) ~ 7e-23 << 1e-20 guard
        if (__any(dmax > -60.f)) {
            bool has_diag = (col0 == wg_row0);   // wave-uniform
#pragma unroll
            for (int ti = 0; ti < 2; ++ti)
#pragma unroll
                for (int r = 0; r < 4; ++r) {
                    int slot = ti * 4 + r;
                    float e[8];
#pragma unroll
                    for (int tj = 0; tj < 8; ++tj)
                        e[tj] = __expf(acc[ti][tj][r] - Mr[slot]);
                    if (has_diag) {
                        // diag element: col tile tj == wid*2+ti, l16 == quad*4+r
                        if (l16 == quad * 4 + r) e[wid * 2 + ti] = 0.f;
                    }
                    s[slot] += ((e[0] + e[1]) + (e[2] + e[3])) +
                               ((e[4] + e[5]) + (e[6] + e[7]));
                }
        }
    }

    // sum across the 16 lanes of each quad (cols), then lane l16==0 writes
#pragma unroll
    for (int slot = 0; slot < 8; ++slot) {
        float ss = s[slot];
#pragma unroll
        for (int off = 1; off < 16; off <<= 1) ss += __shfl_xor(ss, off);
        if (l16 == 0) {
            int ti = slot >> 2, r = slot & 3;
            int row = row0 + ti * 16 + quad * 4 + r;
            ps[ch * N + row] = ss;
        }
    }
}

// ---------------- k_final: merge chunks, per-row term, reduce, finalize ----------------
__global__ void k_final(const float* __restrict__ ps, const float* __restrict__ posdot,
                        const float* __restrict__ diag10, const int* __restrict__ tgt,
                        int* __restrict__ cnt, float* __restrict__ acc,
                        float* __restrict__ out) {
    int i = blockIdx.x * 256 + threadIdx.x;
    float ss = 0.f;
#pragma unroll
    for (int c = 0; c < NCH; ++c) ss += ps[c * N + i];
    float term = diag10[i] + __logf(ss + 1e-20f);
    float np = (float)(cnt[tgt[i]] - 1);
    float mlp = (np < 0.5f) ? 0.f : (10.f * posdot[i] - np * term) / np;
#pragma unroll
    for (int off = 32; off >= 1; off >>= 1) mlp += __shfl_xor(mlp, off);
    __shared__ float wsum[4];
    int lane = threadIdx.x & 63, w = threadIdx.x >> 6;
    if (lane == 0) wsum[w] = mlp;
    __syncthreads();
    if (threadIdx.x == 0) {
        atomicAdd(acc, (wsum[0] + wsum[1]) + (wsum[2] + wsum[3]));
        __threadfence();
        int old = atomicAdd(&cnt[12], 1);   // ticket
        if (old == gridDim.x - 1) {
            float tot = atomicAdd(acc, 0.0f);   // coherent read of the total
            double sp = 0.0, sn = 0.0;
            for (int c = 0; c < NCLS; ++c) {
                double n = (double)cnt[c];
                sp += n * (n - 1.0);
                sn += n * ((double)N - n);
            }
            out[0] = (float)(-(0.1 / 0.07) * ((double)tot / (double)N));
            out[1] = (float)(sp / (double)N);
            out[2] = (float)(sn / (double)N);
        }
    }
}

extern "C" void kernel_launch(void* const* d_in, const int* in_sizes, int n_in,
                              void* d_out, int out_size, void* d_ws, size_t ws_size,
                              hipStream_t stream) {
    const float* F = (const float*)d_in[0];
    const int* tgt = (const int*)d_in[1];
    float* out = (float*)d_out;
    char* ws = (char*)d_ws;

    int* cnt = (int*)(ws);                          // 64 B (incl. ticket at [12])
    float* acc = (float*)(ws + 64);                 // 4 B
    float* S = (float*)(ws + 128);                  // 5120 B
    float* posdot = (float*)(ws + 8192);            // 32 KiB
    float* diag10 = (float*)(ws + 40960);           // 32 KiB
    float* ps = (float*)(ws + 81920);               // NCH*N*4 = 512 KiB
    unsigned short* A10 = (unsigned short*)(ws + (1u << 20));      // 2 MiB (x10 bf16)
    unsigned short* B1 = (unsigned short*)(ws + 3u * (1u << 20));  // 2 MiB (bf16)

    k_zero<<<1, 256, 0, stream>>>(cnt, acc, S);
    k_prep<<<N / 64, 256, 0, stream>>>(F, tgt, S, cnt);
    k_row<<<N / 4, 256, 0, stream>>>(F, tgt, S, posdot, diag10, A10, B1);
    k_pair<<<dim3(N / 128, NCH), 256, 0, stream>>>(A10, B1, diag10, ps);
    k_final<<<N / 256, 256, 0, stream>>>(ps, posdot, diag10, tgt, cnt, acc, out);
}

// Round 3
// 148.311 us; speedup vs baseline: 1.2670x; 1.2670x over previous
//
#include <hip/hip_runtime.h>

#define N 8192
#define KD 128
#define NCLS 10
#define NCH 16
#define CHUNK (N / NCH) /* 512 */
#define NBLK_PREP 512   /* 16 rows per prep block */

typedef __attribute__((ext_vector_type(8))) short short8;
typedef __attribute__((ext_vector_type(4))) float floatx4;

__device__ __forceinline__ unsigned short f2bf(float x) {
    unsigned u = __float_as_uint(x);
    u += 0x7fffu + ((u >> 16) & 1u);   // round-to-nearest-even
    return (unsigned short)(u >> 16);
}

// ---------------- k_prep: bf16 convert + diag + per-block histogram ----------------
// 512 blocks x 256 threads; 16 rows/block; thread t: col4 = t&31, row-group = t>>5
__global__ __launch_bounds__(256) void k_prep(const float* __restrict__ F,
                                              const int* __restrict__ tgt,
                                              float* __restrict__ diag10,
                                              unsigned short* __restrict__ A10,
                                              unsigned short* __restrict__ B1,
                                              int* __restrict__ Hpart) {
    int t = threadIdx.x;
    int row0 = blockIdx.x * 16;
    __shared__ int hist[NCLS];
    if (t < NCLS) hist[t] = 0;
    __syncthreads();
    if (t < 16) atomicAdd(&hist[tgt[row0 + t]], 1);

    int col4 = t & 31;   // which float4 of the row
    int rg = t >> 5;     // 0..7
#pragma unroll
    for (int sw = 0; sw < 2; ++sw) {
        int row = row0 + sw * 8 + rg;
        float4 v = *(const float4*)(F + row * KD + col4 * 4);
        float sq = v.x * v.x + v.y * v.y + v.z * v.z + v.w * v.w;
#pragma unroll
        for (int off = 16; off >= 1; off >>= 1) sq += __shfl_xor(sq, off);
        if (col4 == 0) diag10[row] = 10.f * sq;
        ushort4 a, b;
        a.x = f2bf(10.f * v.x); a.y = f2bf(10.f * v.y);
        a.z = f2bf(10.f * v.z); a.w = f2bf(10.f * v.w);
        b.x = f2bf(v.x); b.y = f2bf(v.y); b.z = f2bf(v.z); b.w = f2bf(v.w);
        *(ushort4*)(A10 + row * KD + col4 * 4) = a;
        *(ushort4*)(B1 + row * KD + col4 * 4) = b;
    }
    __syncthreads();
    if (t < NCLS) Hpart[blockIdx.x * NCLS + t] = hist[t];
}

// ---------------- k_pair: streaming pairwise sum-exp + positive-logit sums ----------------
// Grid: (N/128, NCH). Block 256 = 4 waves of 32 rows. Wave tile 32x128, K=128.
__global__ __launch_bounds__(256, 2) void k_pair(const unsigned short* __restrict__ A10,
                                                 const unsigned short* __restrict__ B1,
                                                 const float* __restrict__ diag10,
                                                 const int* __restrict__ tgt,
                                                 float* __restrict__ ps,
                                                 float* __restrict__ pd) {
    int bx = blockIdx.x, ch = blockIdx.y;
    int tid = threadIdx.x;
    int wid = tid >> 6, lane = tid & 63;
    int quad = lane >> 4, l16 = lane & 15;
    int wg_row0 = bx * 128;
    int row0 = wg_row0 + wid * 32;

    // A fragments resident for the whole sweep: A[m=l16][k=quad*8+j]
    short8 af[2][4];
#pragma unroll
    for (int ti = 0; ti < 2; ++ti)
#pragma unroll
        for (int ks = 0; ks < 4; ++ks) {
            int r = row0 + ti * 16 + l16;
            af[ti][ks] = *(const short8*)(A10 + r * KD + ks * 32 + quad * 8);
        }

    // per-slot row metadata: row = row0 + ti*16 + quad*4 + r
    float Mr[8];
    int crow[8];
#pragma unroll
    for (int ti = 0; ti < 2; ++ti)
#pragma unroll
        for (int r = 0; r < 4; ++r) {
            int row = row0 + ti * 16 + quad * 4 + r;
            Mr[ti * 4 + r] = diag10[row];
            crow[ti * 4 + r] = tgt[row];
        }

    float s[8], p[8];
#pragma unroll
    for (int i = 0; i < 8; ++i) { s[i] = 0.f; p[i] = 0.f; }

    int ccol0 = ch * CHUNK;
    for (int jj = 0; jj < CHUNK / 128; ++jj) {
        int col0 = ccol0 + jj * 128;
        int ccol[8];
#pragma unroll
        for (int tj = 0; tj < 8; ++tj) ccol[tj] = tgt[col0 + tj * 16 + l16];

        floatx4 acc[2][8];
#pragma unroll
        for (int ti = 0; ti < 2; ++ti)
#pragma unroll
            for (int tj = 0; tj < 8; ++tj)
                acc[ti][tj] = (floatx4){0.f, 0.f, 0.f, 0.f};

#pragma unroll
        for (int ks = 0; ks < 4; ++ks) {
            short8 bf[8];                // B[k=quad*8+j][n=l16]
#pragma unroll
            for (int tj = 0; tj < 8; ++tj) {
                int cidx = col0 + tj * 16 + l16;
                bf[tj] = *(const short8*)(B1 + cidx * KD + ks * 32 + quad * 8);
            }
#pragma unroll
            for (int ti = 0; ti < 2; ++ti)
#pragma unroll
                for (int tj = 0; tj < 8; ++tj)
                    acc[ti][tj] = __builtin_amdgcn_mfma_f32_16x16x32_bf16(
                        af[ti][ks], bf[tj], acc[ti][tj], 0, 0, 0);
        }

        bool has_diag = (col0 == wg_row0);   // block-uniform
        float dmax = -1e30f;
#pragma unroll
        for (int ti = 0; ti < 2; ++ti)
#pragma unroll
            for (int r = 0; r < 4; ++r) {
                int slot = ti * 4 + r;
                // tile max for the underflow skip-check
                float mb = fmaxf(
                    fmaxf(fmaxf(acc[ti][0][r], acc[ti][1][r]),
                          fmaxf(acc[ti][2][r], acc[ti][3][r])),
                    fmaxf(fmaxf(acc[ti][4][r], acc[ti][5][r]),
                          fmaxf(acc[ti][6][r], acc[ti][7][r])));
                dmax = fmaxf(dmax, mb - Mr[slot]);
                // positive-logit accumulation (always runs); constant indices only
                float pa = 0.f;
#pragma unroll
                for (int tj = 0; tj < 8; ++tj) {
                    bool sel = (ccol[tj] == crow[slot]);
                    if (has_diag && (tj == wid * 2 + ti))
                        sel = sel && (l16 != quad * 4 + r);   // drop self-pair
                    pa += sel ? acc[ti][tj][r] : 0.f;
                }
                p[slot] += pa;
            }

        // exp(x), x < -60: total mass < 8192*e^-60 ~ 7e-23 << 1e-20 guard
        if (__any(dmax > -60.f)) {
#pragma unroll
            for (int ti = 0; ti < 2; ++ti)
#pragma unroll
                for (int r = 0; r < 4; ++r) {
                    int slot = ti * 4 + r;
                    float sb = 0.f;
#pragma unroll
                    for (int tj = 0; tj < 8; ++tj) {
                        float ev = __expf(acc[ti][tj][r] - Mr[slot]);
                        bool isd = has_diag && (tj == wid * 2 + ti) &&
                                   (l16 == quad * 4 + r);
                        sb += isd ? 0.f : ev;
                    }
                    s[slot] += sb;
                }
        }
    }

    // reduce across the 16 lanes of each quad (cols); lane l16==0 writes
#pragma unroll
    for (int slot = 0; slot < 8; ++slot) {
        float ss = s[slot], pp = p[slot];
#pragma unroll
        for (int off = 1; off < 16; off <<= 1) {
            ss += __shfl_xor(ss, off);
            pp += __shfl_xor(pp, off);
        }
        if (l16 == 0) {
            int ti = slot >> 2, r = slot & 3;
            int row = row0 + ti * 16 + quad * 4 + r;
            ps[row * NCH + ch] = ss;
            pd[row * NCH + ch] = pp;
        }
    }
}

// ---------------- k_final: single block, merge chunks + finalize ----------------
__global__ __launch_bounds__(1024) void k_final(const float* __restrict__ ps,
                                                const float* __restrict__ pd,
                                                const float* __restrict__ diag10,
                                                const int* __restrict__ tgt,
                                                const int* __restrict__ Hpart,
                                                float* __restrict__ out) {
    int t = threadIdx.x;
    __shared__ int cnt_s[NCLS];
    if (t < NCLS) cnt_s[t] = 0;
    __syncthreads();
    for (int idx = t; idx < NBLK_PREP * NCLS; idx += 1024)
        atomicAdd(&cnt_s[idx % NCLS], Hpart[idx]);
    __syncthreads();

    float local = 0.f;
    for (int r = t; r < N; r += 1024) {
        float ss = 0.f, pp = 0.f;
        const float4* psv = (const float4*)(ps + r * NCH);
        const float4* pdv = (const float4*)(pd + r * NCH);
#pragma unroll
        for (int i = 0; i < NCH / 4; ++i) {
            float4 a = psv[i]; ss += (a.x + a.y) + (a.z + a.w);
            float4 b = pdv[i]; pp += (b.x + b.y) + (b.z + b.w);
        }
        float np = (float)(cnt_s[tgt[r]] - 1);
        float term = diag10[r] + __logf(ss + 1e-20f);
        local += (np < 0.5f) ? 0.f : (pp - np * term) / np;
    }
#pragma unroll
    for (int off = 32; off >= 1; off >>= 1) local += __shfl_xor(local, off);
    __shared__ float wsum[16];
    if ((t & 63) == 0) wsum[t >> 6] = local;
    __syncthreads();
    if (t == 0) {
        float tot = 0.f;
        for (int i = 0; i < 16; ++i) tot += wsum[i];
        double sp = 0.0, sn = 0.0;
        for (int c = 0; c < NCLS; ++c) {
            double n = (double)cnt_s[c];
            sp += n * (n - 1.0);
            sn += n * ((double)N - n);
        }
        out[0] = (float)(-(0.1 / 0.07) * ((double)tot / (double)N));
        out[1] = (float)(sp / (double)N);
        out[2] = (float)(sn / (double)N);
    }
}

extern "C" void kernel_launch(void* const* d_in, const int* in_sizes, int n_in,
                              void* d_out, int out_size, void* d_ws, size_t ws_size,
                              hipStream_t stream) {
    const float* F = (const float*)d_in[0];
    const int* tgt = (const int*)d_in[1];
    float* out = (float*)d_out;
    char* ws = (char*)d_ws;

    float* diag10 = (float*)(ws);                       // 32 KiB
    int* Hpart = (int*)(ws + 32768);                    // 20 KiB
    float* ps = (float*)(ws + 65536);                   // 512 KiB
    float* pd = (float*)(ws + 65536 + NCH * N * 4);     // 512 KiB
    unsigned short* A10 = (unsigned short*)(ws + (2u << 20));  // 2 MiB
    unsigned short* B1 = (unsigned short*)(ws + (4u << 20));   // 2 MiB

    k_prep<<<NBLK_PREP, 256, 0, stream>>>(F, tgt, diag10, A10, B1, Hpart);
    k_pair<<<dim3(N / 128, NCH), 256, 0, stream>>>(A10, B1, diag10, tgt, ps, pd);
    k_final<<<1, 1024, 0, stream>>>(ps, pd, diag10, tgt, Hpart, out);
}

// Round 4
// 104.396 us; speedup vs baseline: 1.8000x; 1.4207x over previous
//
#include <hip/hip_runtime.h>

#define N 8192
#define KD 128
#define NCLS 10
#define NCH 8
#define NCH2 (NCH * 2)       /* 16 col-partials per row (2 waves per 128-col tile) */
#define CHUNK (N / NCH)      /* 1024 cols per block, 8 jj-tiles of 128 */

typedef __attribute__((ext_vector_type(8))) short short8;
typedef __attribute__((ext_vector_type(4))) float floatx4;

__device__ __forceinline__ unsigned short f2bf(float x) {
    unsigned u = __float_as_uint(x);
    u += 0x7fffu + ((u >> 16) & 1u);   // round-to-nearest-even
    return (unsigned short)(u >> 16);
}

// ---------------- k_prep: bf16 convert (B1 swizzled) + diag + hist->cnt ----------------
// 512 blocks x 256 threads; 16 rows/block. t = rg*32 + col4.
__global__ __launch_bounds__(256) void k_prep(const float* __restrict__ F,
                                              const int* __restrict__ tgt,
                                              float* __restrict__ diag10,
                                              unsigned short* __restrict__ A10,
                                              unsigned short* __restrict__ B1,
                                              int* __restrict__ cnt) {
    int t = threadIdx.x;
    int row0 = blockIdx.x * 16;
    __shared__ int hist[NCLS];
    if (t < NCLS) hist[t] = 0;
    __syncthreads();
    if (t < 16) atomicAdd(&hist[tgt[row0 + t]], 1);

    int col4 = t & 31;   // which float4 of the row (k = col4*4)
    int rg = t >> 5;     // 0..7
#pragma unroll
    for (int sw = 0; sw < 2; ++sw) {
        int row = row0 + sw * 8 + rg;
        float4 v = *(const float4*)(F + (size_t)row * KD + col4 * 4);
        float sq = v.x * v.x + v.y * v.y + v.z * v.z + v.w * v.w;
#pragma unroll
        for (int off = 16; off >= 1; off >>= 1) sq += __shfl_xor(sq, off);
        if (col4 == 0) diag10[row] = 10.f * sq;
        ushort4 a, b;
        a.x = f2bf(10.f * v.x); a.y = f2bf(10.f * v.y);
        a.z = f2bf(10.f * v.z); a.w = f2bf(10.f * v.w);
        b.x = f2bf(v.x); b.y = f2bf(v.y); b.z = f2bf(v.z); b.w = f2bf(v.w);
        *(ushort4*)(A10 + (size_t)row * KD + col4 * 4) = a;
        // B1 stored with XOR-swizzled 16B blocks within each row:
        // block kb = col4>>1 goes to kb ^ (row & 15); 8B half preserved.
        int kb = col4 >> 1, half = col4 & 1;
        int swo = ((kb ^ (row & 15)) << 3) + (half << 2);   // ushort units
        *(ushort4*)(B1 + (size_t)row * KD + swo) = b;
    }
    __syncthreads();
    if (t < NCLS) atomicAdd(&cnt[t], hist[t]);
}

// ---------------- k_pair: LDS-staged streaming sum-exp + positive-logit sums --------
// Grid (64, 8). Block = 4 waves in 2x2 grid of 64x64 wave tiles over a 128-row slab;
// per jj a 128x128 B tile is DMA-staged to LDS (double-buffered, XOR-swizzled).
__global__ __launch_bounds__(256, 2) void k_pair(const unsigned short* __restrict__ A10,
                                                 const unsigned short* __restrict__ B1,
                                                 const float* __restrict__ diag10,
                                                 const int* __restrict__ tgt,
                                                 float* __restrict__ PS,
                                                 float* __restrict__ PD) {
    __shared__ unsigned short Bs[2][128 * KD];   // 2 x 32 KiB = 64 KiB exactly
    int bx = blockIdx.x, ch = blockIdx.y;
    int tid = threadIdx.x;
    int wid = tid >> 6, lane = tid & 63;
    int quad = lane >> 4, l16 = lane & 15;
    int wrow = wid >> 1, wcol = wid & 1;
    int row0w = bx * 128 + wrow * 64;            // this wave's 64 rows

    // stage jj=0 first so DMA overlaps the prologue loads
    {
        const unsigned char* g = (const unsigned char*)B1 + (size_t)(ch * CHUNK) * KD * 2;
        unsigned off = wid * 1024u + lane * 16u;
#pragma unroll
        for (int i = 0; i < 8; ++i)
            __builtin_amdgcn_global_load_lds(
                (const __attribute__((address_space(1))) void*)(g + i * 4096 + off),
                (__attribute__((address_space(3))) void*)((unsigned char*)&Bs[0][0] + i * 4096 + wid * 1024),
                16, 0, 0);
    }

    // A fragments resident: af[ti][ks], rows row0w + ti*16 + l16
    short8 af[4][4];
#pragma unroll
    for (int ti = 0; ti < 4; ++ti)
#pragma unroll
        for (int ks = 0; ks < 4; ++ks)
            af[ti][ks] = *(const short8*)(A10 + (size_t)(row0w + ti * 16 + l16) * KD + ks * 32 + quad * 8);

    float Mr[16];
    int crow[16];
#pragma unroll
    for (int ti = 0; ti < 4; ++ti)
#pragma unroll
        for (int r = 0; r < 4; ++r) {
            int row = row0w + ti * 16 + quad * 4 + r;
            Mr[ti * 4 + r] = diag10[row];
            crow[ti * 4 + r] = tgt[row];
        }

    float s[16], p[16];
#pragma unroll
    for (int i = 0; i < 16; ++i) { s[i] = 0.f; p[i] = 0.f; }

    asm volatile("s_waitcnt vmcnt(0)" ::: "memory");
    __syncthreads();

    for (int jj = 0; jj < CHUNK / 128; ++jj) {
        int buf = jj & 1;
        int col0w = ch * CHUNK + jj * 128 + wcol * 64;   // this wave's 64 cols

        // column classes for selection (global, L2-hot; consumed in epilogue)
        int ccol[4];
#pragma unroll
        for (int tj = 0; tj < 4; ++tj) ccol[tj] = tgt[col0w + tj * 16 + l16];

        // prefetch next tile into the other buffer
        if (jj + 1 < CHUNK / 128) {
            const unsigned char* g = (const unsigned char*)B1 +
                (size_t)(ch * CHUNK + (jj + 1) * 128) * KD * 2;
            unsigned off = wid * 1024u + lane * 16u;
#pragma unroll
            for (int i = 0; i < 8; ++i)
                __builtin_amdgcn_global_load_lds(
                    (const __attribute__((address_space(1))) void*)(g + i * 4096 + off),
                    (__attribute__((address_space(3))) void*)((unsigned char*)&Bs[buf ^ 1][0] + i * 4096 + wid * 1024),
                    16, 0, 0);
        }

        floatx4 acc[4][4];
#pragma unroll
        for (int ti = 0; ti < 4; ++ti)
#pragma unroll
            for (int tj = 0; tj < 4; ++tj)
                acc[ti][tj] = (floatx4){0.f, 0.f, 0.f, 0.f};

        const unsigned short* bs = &Bs[buf][0];
#pragma unroll
        for (int ks = 0; ks < 4; ++ks) {
            short8 bfr[4];
#pragma unroll
            for (int tj = 0; tj < 4; ++tj) {
                int lr = wcol * 64 + tj * 16 + l16;                 // local B row (col)
                int off = lr * KD + (((ks * 4 + quad) ^ l16) << 3); // swizzled 16B block
                bfr[tj] = *(const short8*)(bs + off);
            }
#pragma unroll
            for (int ti = 0; ti < 4; ++ti)
#pragma unroll
                for (int tj = 0; tj < 4; ++tj)
                    acc[ti][tj] = __builtin_amdgcn_mfma_f32_16x16x32_bf16(
                        af[ti][ks], bfr[tj], acc[ti][tj], 0, 0, 0);
        }

        bool hd = (col0w == row0w);   // wave-uniform diag tile
        float dmax = -1e30f;
#pragma unroll
        for (int ti = 0; ti < 4; ++ti)
#pragma unroll
            for (int r = 0; r < 4; ++r) {
                int slot = ti * 4 + r;
                float mb = fmaxf(fmaxf(acc[ti][0][r], acc[ti][1][r]),
                                 fmaxf(acc[ti][2][r], acc[ti][3][r]));
                dmax = fmaxf(dmax, mb - Mr[slot]);
                float pa = 0.f;
#pragma unroll
                for (int tj = 0; tj < 4; ++tj) {
                    bool sel = (ccol[tj] == crow[slot]);
                    if (hd && (tj == ti)) sel = sel && (l16 != quad * 4 + r);
                    pa += sel ? acc[ti][tj][r] : 0.f;
                }
                p[slot] += pa;
            }

        // exp(x), x < -60: total skipped mass < 8192*e^-60 ~ 7e-23 << 1e-20 guard
        if (__any(dmax > -60.f)) {
#pragma unroll
            for (int ti = 0; ti < 4; ++ti)
#pragma unroll
                for (int r = 0; r < 4; ++r) {
                    int slot = ti * 4 + r;
                    float sb = 0.f;
#pragma unroll
                    for (int tj = 0; tj < 4; ++tj) {
                        float ev = __expf(acc[ti][tj][r] - Mr[slot]);
                        bool isd = hd && (tj == ti) && (l16 == quad * 4 + r);
                        sb += isd ? 0.f : ev;
                    }
                    s[slot] += sb;
                }
        }

        asm volatile("s_waitcnt vmcnt(0)" ::: "memory");
        __syncthreads();
    }

    // reduce over the 16 col-lanes of each quad; lane l16==0 writes partials
    int ch2 = ch * 2 + wcol;
#pragma unroll
    for (int ti = 0; ti < 4; ++ti)
#pragma unroll
        for (int r = 0; r < 4; ++r) {
            int slot = ti * 4 + r;
            float ss = s[slot], pp = p[slot];
#pragma unroll
            for (int off = 1; off < 16; off <<= 1) {
                ss += __shfl_xor(ss, off);
                pp += __shfl_xor(pp, off);
            }
            if (l16 == 0) {
                int row = row0w + ti * 16 + quad * 4 + r;
                PS[(size_t)ch2 * N + row] = ss;
                PD[(size_t)ch2 * N + row] = pp;
            }
        }
}

// ---------------- k_final: merge partials, per-row term, reduce, finalize ----------------
__global__ __launch_bounds__(256) void k_final(const float* __restrict__ PS,
                                               const float* __restrict__ PD,
                                               const float* __restrict__ diag10,
                                               const int* __restrict__ tgt,
                                               int* __restrict__ cnt,
                                               float* __restrict__ acc,
                                               float* __restrict__ out) {
    int r = blockIdx.x * 256 + threadIdx.x;
    float ss = 0.f, pp = 0.f;
#pragma unroll
    for (int c2 = 0; c2 < NCH2; ++c2) {
        ss += PS[(size_t)c2 * N + r];
        pp += PD[(size_t)c2 * N + r];
    }
    float term = diag10[r] + __logf(ss + 1e-20f);
    float np = (float)(cnt[tgt[r]] - 1);
    float mlp = (np < 0.5f) ? 0.f : (pp - np * term) / np;
#pragma unroll
    for (int off = 32; off >= 1; off >>= 1) mlp += __shfl_xor(mlp, off);
    __shared__ float wsum[4];
    int lane = threadIdx.x & 63, w = threadIdx.x >> 6;
    if (lane == 0) wsum[w] = mlp;
    __syncthreads();
    if (threadIdx.x == 0) {
        atomicAdd(acc, (wsum[0] + wsum[1]) + (wsum[2] + wsum[3]));
        __threadfence();
        int old = atomicAdd(&cnt[12], 1);   // ticket
        if (old == (int)gridDim.x - 1) {
            float tot = atomicAdd(acc, 0.0f);   // coherent read of total
            double sp = 0.0, sn = 0.0;
            for (int c = 0; c < NCLS; ++c) {
                double n = (double)cnt[c];
                sp += n * (n - 1.0);
                sn += n * ((double)N - n);
            }
            out[0] = (float)(-(0.1 / 0.07) * ((double)tot / (double)N));
            out[1] = (float)(sp / (double)N);
            out[2] = (float)(sn / (double)N);
        }
    }
}

extern "C" void kernel_launch(void* const* d_in, const int* in_sizes, int n_in,
                              void* d_out, int out_size, void* d_ws, size_t ws_size,
                              hipStream_t stream) {
    const float* F = (const float*)d_in[0];
    const int* tgt = (const int*)d_in[1];
    float* out = (float*)d_out;
    char* ws = (char*)d_ws;

    int* cnt = (int*)(ws);                              // 64 B (ticket at [12])
    float* acc = (float*)(ws + 64);                     // 4 B
    float* diag10 = (float*)(ws + 256);                 // 32 KiB  -> ends 33024
    float* PS = (float*)(ws + 65536);                   // 512 KiB -> ends 589824
    float* PD = (float*)(ws + 589824);                  // 512 KiB -> ends 1114112
    unsigned short* A10 = (unsigned short*)(ws + 1114112);   // 2 MiB -> ends 3211264
    unsigned short* B1 = (unsigned short*)(ws + 3211264);    // 2 MiB -> ends ~5.06 MiB

    hipMemsetAsync(ws, 0, 128, stream);                 // cnt + ticket + acc
    k_prep<<<N / 16, 256, 0, stream>>>(F, tgt, diag10, A10, B1, cnt);
    k_pair<<<dim3(N / 128, NCH), 256, 0, stream>>>(A10, B1, diag10, tgt, PS, PD);
    k_final<<<N / 256, 256, 0, stream>>>(PS, PD, diag10, tgt, cnt, acc, out);
}